// Round 10
// baseline (4059.708 us; speedup 1.0000x reference)
//
#include <hip/hip_runtime.h>
#include <stdint.h>

typedef unsigned short u16;
typedef unsigned char u8;
typedef unsigned long long u64;
typedef short s16x8 __attribute__((ext_vector_type(8)));
typedef float f32x4 __attribute__((ext_vector_type(4)));
typedef float f32x2 __attribute__((ext_vector_type(2)));
typedef unsigned int u32x4 __attribute__((ext_vector_type(4)));
typedef unsigned int u32x2 __attribute__((ext_vector_type(2)));

#define NB 128
#define NT 512
#define NH 256
#define GQ 8      // batch groups
#define MBQ 16    // batch rows per group
#define STEPS 511

// ---- workspace layout (bytes) ----
// outbox: [parity][grp][j][row16][chunk32] u64 = 2*8*4*16*32*8 = 131072
#define WS_OBOX 0
#define WS_X12  131072   // 12*64 floats = 3072

// ---- dynamic LDS layout (bytes) ----
#define OFF_H     0        // h tile:   16 rows * 264 u16 = 8448
#define OFF_PRE   8448     // pre:      7 gates * 16 * 72 u16 = 16128
#define OFF_G     24576    // gates:    7 * 16 * 68 f32 = 30464
#define OFF_XC    55040    // xc table: 7 * 64 * 13 f32 = 23296
#define OFF_B2    78336    // g_b2 slice: 7*64 f32 = 1792
#define OFF_IW    80128    // i_W slice: 64 f32 = 256
#define OFF_X12   80384    // x12: 12*64 f32 = 3072
#define OFF_IDXA  83456    // idx_all: 511*16 u8 -> 8192
#define OFF_DTA   91648    // dt_all: 511*16 f32 = 32704
#define SMEM_BYTES 124416

__device__ __forceinline__ u16 f2bf(float f) {
  unsigned u = __float_as_uint(f);
  u += 0x7FFFu + ((u >> 16) & 1u);  // round-to-nearest-even
  return (u16)(u >> 16);
}
__device__ __forceinline__ float sigm(float x) { return 1.0f / (1.0f + __expf(-x)); }
__device__ __forceinline__ float tanh_fast(float x) {
  float e = __expf(2.0f * x);
  return 1.0f - 2.0f / (e + 1.0f);   // NaN-free: x->+inf => 1, x->-inf => -1
}
__device__ __forceinline__ float softplus_f(float x) {
  return fmaxf(x, 0.0f) + __logf(1.0f + __expf(-fabsf(x)));
}
__device__ __forceinline__ u64 ald64(const u64* p) {
  return __hip_atomic_load(p, __ATOMIC_RELAXED, __HIP_MEMORY_SCOPE_AGENT);
}
__device__ __forceinline__ void ast64(u64* p, u64 v) {
  __hip_atomic_store(p, v, __ATOMIC_RELAXED, __HIP_MEMORY_SCOPE_AGENT);
}

// ---------------- prep: 12 embeddings, zero BOTH outbox parities ----------------
__global__ void ct4_prep(const float* __restrict__ etW1, const float* __restrict__ etb1,
                         const float* __restrict__ etW2, const float* __restrict__ etb2,
                         const float* __restrict__ esW1, const float* __restrict__ esb1,
                         const float* __restrict__ esW2, const float* __restrict__ esb2,
                         char* __restrict__ ws) {
  __shared__ float sT[4][64];
  __shared__ float sS[3][64];
  const int i = threadIdx.x;  // 64 threads
  #pragma unroll
  for (int e = 0; e < 4; ++e) sT[e][i] = tanhf(etW1[i * 4 + e] + etb1[i]);
  #pragma unroll
  for (int s = 0; s < 3; ++s) sS[s][i] = tanhf(esW1[i * 3 + s] + esb1[i]);
  __syncthreads();
  float te[4], se[3];
  #pragma unroll
  for (int e = 0; e < 4; ++e) {
    float a = etb2[i];
    for (int jj = 0; jj < 64; ++jj) a += sT[e][jj] * etW2[i * 64 + jj];
    te[e] = tanhf(a);
  }
  #pragma unroll
  for (int s = 0; s < 3; ++s) {
    float a = esb2[i];
    for (int jj = 0; jj < 64; ++jj) a += sS[s][jj] * esW2[i * 64 + jj];
    se[s] = tanhf(a);
  }
  float* x12 = (float*)(ws + WS_X12);
  #pragma unroll
  for (int e = 0; e < 4; ++e)
    #pragma unroll
    for (int s = 0; s < 3; ++s) x12[(e * 3 + s) * 64 + i] = te[e] + se[s];
  // zero the ENTIRE outbox (both parities, 131072 B) - stale tags from a previous
  // graph replay would otherwise alias current-step tags.
  u32x4* hz = (u32x4*)(ws + WS_OBOX);
  u32x4 z = {0u, 0u, 0u, 0u};
  for (int p = i; p < 131072 / 16; p += 64) hz[p] = z;
}

// ---------------- main persistent recurrence kernel ----------------
// r8 structure, exchange replaced by tag-embedded chunks:
// Per step the ONLY fabric latency on the critical path is one-way store + poll RT.
// Each phase-C thread publishes its 2 bf16 of h(t+1) + tag (t+1) as ONE relaxed
// agent-scope u64 (atomic -> tag and data arrive together; no drain, no flag).
// Wave 7 polls 24 chunks (8 per partner block) until tags match, writes LDS.
__global__ __launch_bounds__(512, 1) void ct4_main(
    const int* __restrict__ ev, const float* __restrict__ ts, const int* __restrict__ mk,
    const float* __restrict__ gW1, const float* __restrict__ gb1,
    const float* __restrict__ gW2, const float* __restrict__ gb2,
    const float* __restrict__ iW, const float* __restrict__ ibp,
    float* __restrict__ out, char* __restrict__ ws) {
  extern __shared__ char smem[];
  u16* h_lds = (u16*)(smem + OFF_H);          // [16][264]
  float* g_lds = (float*)(smem + OFF_G);      // [7][16][68]
  float* xc_lds = (float*)(smem + OFF_XC);    // [(k*64+o)*13 + m]
  float* b2_lds = (float*)(smem + OFF_B2);    // [7][64]
  float* iw_lds = (float*)(smem + OFF_IW);    // [64]
  float* x12_lds = (float*)(smem + OFF_X12);  // [12][64]
  u8* idx_all = (u8*)(smem + OFF_IDXA);       // [511*16]
  float* dt_all = (float*)(smem + OFF_DTA);   // [511*16]

  const int tid = threadIdx.x;
  const int bid = blockIdx.x;
  const int grp = bid & 7;
  const int j = bid >> 3;
  const int b0 = grp * MBQ;
  const int wave = tid >> 6;
  const int q = (tid >> 4) & 3;
  const int c = tid & 15;
  const int kloc0 = 2 * j;  // local K tiles (32-wide) are {2j, 2j+1}

  u64* obox = (u64*)(ws + WS_OBOX);  // [parity*8+grp][j][row16][chunk32]

  // ---- prologue ----
  for (int p = tid; p < 12 * 64; p += 512) x12_lds[p] = ((const float*)(ws + WS_X12))[p];
  for (int p = tid; p < 16 * 264 / 2; p += 512) ((unsigned*)h_lds)[p] = 0u;  // h(0)=0
  if (tid < 448) {
    int kk = tid >> 6, o = tid & 63;
    b2_lds[kk * 64 + o] = gb2[kk * 256 + j * 64 + o];
  }
  if (tid < 64) iw_lds[tid] = iW[j * 256 + j * 64 + tid];
  const float ibj = ibp[j];
  // preload all per-step indices / dts into LDS
  for (int p = tid; p < STEPS * 16; p += 512) {
    int t = p >> 4, b = p & 15;
    idx_all[p] = (u8)(ev[(b0 + b) * NT + t] * 3 + mk[(b0 + b) * NT + t]);
    dt_all[p] = ts[(b0 + b) * NT + t + 1];
  }
  __syncthreads();
  // xc table: xc[k][o][m] = g_b1[k][j*64+o] + sum_i x12[m][i] * W1[k][j*64+o][i]
  if (tid < 448) {
    int kk = tid >> 6, o = tid & 63;
    const float* row = gW1 + (size_t)(kk * 256 + j * 64 + o) * 320;
    float a[12];
    float bb = gb1[kk * 256 + j * 64 + o];
    #pragma unroll
    for (int m = 0; m < 12; ++m) a[m] = bb;
    for (int i = 0; i < 64; ++i) {
      float w = row[i];
      #pragma unroll
      for (int m = 0; m < 12; ++m) a[m] += x12_lds[m * 64 + i] * w;
    }
    #pragma unroll
    for (int m = 0; m < 12; ++m) xc_lds[(kk * 64 + o) * 13 + m] = a[m];
  }

  // weight fragments (bf16). Slot order: s=0..5 remote K tiles (kt = s + (s>=2j ? 2:0)),
  // s=6..7 local K tiles (kt = 2j, 2j+1). One gate per wave (wave 7: exchange duty).
  s16x8 a1[4][8];  // W1 h-part: M=64 (o), K=256 (h)
  s16x8 a2[4][2];  // W2 block:  M=64 (o), K=64 (g)
  const int k = wave;
  if (wave < 7) {
    #pragma unroll
    for (int s = 0; s < 8; ++s) {
      int kt = (s < 6) ? (s + (s >= kloc0 ? 2 : 0)) : (kloc0 + (s - 6));
      #pragma unroll
      for (int mt = 0; mt < 4; ++mt) {
        const float* p = gW1 + (size_t)(k * 256 + j * 64 + 16 * mt + c) * 320 + 64 + 32 * kt + 8 * q;
        union { s16x8 v; u16 u[8]; } fr;
        #pragma unroll
        for (int i = 0; i < 8; ++i) fr.u[i] = f2bf(p[i]);
        a1[mt][s] = fr.v;
      }
    }
    #pragma unroll
    for (int mt = 0; mt < 4; ++mt)
      #pragma unroll
      for (int kt = 0; kt < 2; ++kt) {
        const float* p = gW2 + (size_t)(k * 256 + j * 64 + 16 * mt + c) * 256 + j * 64 + 32 * kt + 8 * q;
        union { s16x8 v; u16 u[8]; } fr;
        #pragma unroll
        for (int i = 0; i < 8; ++i) fr.u[i] = f2bf(p[i]);
        a2[mt][kt] = fr.v;
      }
  }

  float ccA[2] = {0.f, 0.f};   // c state
  float cctA[2] = {0.f, 0.f};  // c_target state
  f32x4 acc[4] = {};           // GEMM1 accumulator (local tiles pre-accumulated at bottom)
  const f32x4 fzero = {};
  __syncthreads();

  const int O_CELL = NB * STEPS * 4;
  const int SZB = NB * STEPS * NH;
  const int O_CT = O_CELL + SZB;
  const int O_OUT = O_CT + SZB;
  const int O_DEC = O_OUT + SZB;

  for (int t = 0; t < STEPS; ++t) {
    // ---- top: GEMM1 remote tiles, tanh, GEMM2 ----
    if (wave < 7) {
      #pragma unroll
      for (int s = 0; s < 6; ++s) {
        int ks = s + (s >= kloc0 ? 2 : 0);
        s16x8 bf = *(const s16x8*)&h_lds[c * 264 + 32 * ks + 8 * q];
        #pragma unroll
        for (int mt = 0; mt < 4; ++mt)
          acc[mt] = __builtin_amdgcn_mfma_f32_16x16x32_bf16(a1[mt][s], bf, acc[mt], 0, 0, 0);
      }
      u16* preW = (u16*)(smem + OFF_PRE) + k * (16 * 72);
      int midx = (int)idx_all[t * 16 + c];
      #pragma unroll
      for (int mt = 0; mt < 4; ++mt) {
        int o = 16 * mt + 4 * q;
        const float* xr = &xc_lds[(k * 64 + o) * 13 + midx];
        u16 u0 = f2bf(tanh_fast(acc[mt][0] + xr[0]));
        u16 u1 = f2bf(tanh_fast(acc[mt][1] + xr[13]));
        u16 u2 = f2bf(tanh_fast(acc[mt][2] + xr[26]));
        u16 u3 = f2bf(tanh_fast(acc[mt][3] + xr[39]));
        u32x2 pk;
        pk[0] = (unsigned)u0 | ((unsigned)u1 << 16);
        pk[1] = (unsigned)u2 | ((unsigned)u3 << 16);
        *(u32x2*)&preW[c * 72 + o] = pk;  // pre[b=c][o..o+3], bf16
      }
      f32x4 acc2[4] = {};
      #pragma unroll
      for (int kt = 0; kt < 2; ++kt) {
        s16x8 pf = *(const s16x8*)&preW[c * 72 + 32 * kt + 8 * q];
        #pragma unroll
        for (int mt = 0; mt < 4; ++mt)
          acc2[mt] = __builtin_amdgcn_mfma_f32_16x16x32_bf16(a2[mt][kt], pf, acc2[mt], 0, 0, 0);
      }
      #pragma unroll
      for (int mt = 0; mt < 4; ++mt)
        *(f32x4*)&g_lds[(k * 16 + c) * 68 + 16 * mt + 4 * q] = acc2[mt];
    }
    __syncthreads();  // sync1: g_lds ready

    // ---- phase C: gates, cell update, h_new ----
    const int b = tid >> 5, o2 = (tid & 31) * 2;
    float ip = 0.f;
    float ci[2], ctn[2], opv[2], dcv[2];
    unsigned hp = 0;
    {
      float dtv = dt_all[t * 16 + b];
      float G[7][2];
      #pragma unroll
      for (int kk = 0; kk < 7; ++kk) {
        f32x2 gg = *(const f32x2*)&g_lds[(kk * 16 + b) * 68 + o2];
        G[kk][0] = gg[0] + b2_lds[kk * 64 + o2];
        G[kk][1] = gg[1] + b2_lds[kk * 64 + o2 + 1];
      }
      float hnv[2];
      #pragma unroll
      for (int e = 0; e < 2; ++e) {
        float inp = sigm(G[0][e]);
        float fg = sigm(G[1][e]);
        float op = sigm(G[2][e]);
        float itg = sigm(G[3][e]);
        float ftg = sigm(G[4][e]);
        float z = tanh_fast(G[5][e]);
        float dc = softplus_f(G[6][e]);
        float c_i = fg * ccA[e] + inp * z;
        float c_t = ftg * cctA[e] + itg * z;
        float edv = __expf(-dc * dtv);
        float c_n = c_t + (c_i - c_t) * edv;
        float h_n = op * tanh_fast(c_n);
        ccA[e] = c_n;
        cctA[e] = c_t;
        ci[e] = c_i; ctn[e] = c_t; opv[e] = op; dcv[e] = dc;
        hnv[e] = h_n;
        ip += iw_lds[o2 + e] * h_n;
      }
      if (t < STEPS - 1) {
        hp = (unsigned)f2bf(hnv[0]) | ((unsigned)f2bf(hnv[1]) << 16);
        *(unsigned*)&h_lds[b * 264 + j * 64 + o2] = hp;  // local columns of h(t+1)
      }
    }
    __syncthreads();  // sync2: h_lds local writes ordered (no fabric wait - no stores pending)

    // C2: output stores + intensity (L2-backed)
    auto C2 = [&]() {
      size_t base = ((size_t)(b0 + b) * STEPS + t) * NH + j * 64 + o2;
      f32x2 v;
      v[0] = ci[0];  v[1] = ci[1];  *(f32x2*)&out[O_CELL + base] = v;
      v[0] = ctn[0]; v[1] = ctn[1]; *(f32x2*)&out[O_CT + base] = v;
      v[0] = opv[0]; v[1] = opv[1]; *(f32x2*)&out[O_OUT + base] = v;
      v[0] = dcv[0]; v[1] = dcv[1]; *(f32x2*)&out[O_DEC + base] = v;
      #pragma unroll
      for (int d = 1; d < 32; d <<= 1) ip += __shfl_xor(ip, d, 32);
      if ((tid & 31) == 0)
        out[((size_t)(b0 + b) * STEPS + t) * 4 + j] = softplus_f(ip + ibj);
    };

    if (t < STEPS - 1) {
      // publish h(t+1): ONE self-tagged atomic u64 per thread, one-way, no drain
      ast64(&obox[(size_t)((((t + 1) & 1) * GQ + grp) * 4 + j) * 512 + b * 32 + (tid & 31)],
            ((u64)(unsigned)(t + 1) << 32) | (u64)hp);
      if (wave < 7) {
        // GEMM1 local tiles of h(t+1) while the exchange is in flight
        #pragma unroll
        for (int mt = 0; mt < 4; ++mt) acc[mt] = fzero;
        #pragma unroll
        for (int s = 6; s < 8; ++s) {
          int ks = kloc0 + (s - 6);
          s16x8 bf = *(const s16x8*)&h_lds[c * 264 + 32 * ks + 8 * q];
          #pragma unroll
          for (int mt = 0; mt < 4; ++mt)
            acc[mt] = __builtin_amdgcn_mfma_f32_16x16x32_bf16(a1[mt][s], bf, acc[mt], 0, 0, 0);
        }
        C2();
      } else {
        C2();
        // wave 7: poll 24 tagged chunks (8 per partner), then write LDS
        const int l = tid & 63;
        const int row = l >> 2;
        const int seg = l & 3;
        u64* ob = obox + (size_t)(((t + 1) & 1) * GQ + grp) * 4 * 512;
        const int jr0 = 0 + (0 >= j), jr1 = 1 + (1 >= j), jr2 = 2 + (2 >= j);
        u64* p0 = ob + jr0 * 512 + row * 32 + seg * 8;
        u64* p1 = ob + jr1 * 512 + row * 32 + seg * 8;
        u64* p2 = ob + jr2 * 512 + row * 32 + seg * 8;
        const u64 want = (u64)(unsigned)(t + 1);
        u64 v0[8], v1[8], v2[8];
        unsigned pend = 0xFFFFFFu;
        for (;;) {
          #pragma unroll
          for (int i = 0; i < 8; ++i) {
            if (pend & (1u << i)) v0[i] = ald64(p0 + i);
            if (pend & (1u << (8 + i))) v1[i] = ald64(p1 + i);
            if (pend & (1u << (16 + i))) v2[i] = ald64(p2 + i);
          }
          unsigned np = 0;
          #pragma unroll
          for (int i = 0; i < 8; ++i) {
            if ((v0[i] >> 32) != want) np |= (1u << i);
            if ((v1[i] >> 32) != want) np |= (1u << (8 + i));
            if ((v2[i] >> 32) != want) np |= (1u << (16 + i));
          }
          pend = np;
          if (!pend) break;
        }
        char* lb = (char*)h_lds + row * 528;
        #pragma unroll
        for (int i = 0; i < 8; i += 2) {
          u32x2 w;
          w[0] = (unsigned)v0[i]; w[1] = (unsigned)v0[i + 1];
          *(u32x2*)(lb + jr0 * 128 + (seg * 8 + i) * 4) = w;
          w[0] = (unsigned)v1[i]; w[1] = (unsigned)v1[i + 1];
          *(u32x2*)(lb + jr1 * 128 + (seg * 8 + i) * 4) = w;
          w[0] = (unsigned)v2[i]; w[1] = (unsigned)v2[i + 1];
          *(u32x2*)(lb + jr2 * 128 + (seg * 8 + i) * 4) = w;
        }
      }
      __syncthreads();  // sync3: remote h in LDS visible to all waves
    } else {
      C2();
    }
  }
}

extern "C" void kernel_launch(void* const* d_in, const int* in_sizes, int n_in,
                              void* d_out, int out_size, void* d_ws, size_t ws_size,
                              hipStream_t stream) {
  const int* ev = (const int*)d_in[0];
  const float* ts = (const float*)d_in[1];
  const int* mk = (const int*)d_in[2];
  const float* etW1 = (const float*)d_in[3];
  const float* etb1 = (const float*)d_in[4];
  const float* etW2 = (const float*)d_in[5];
  const float* etb2 = (const float*)d_in[6];
  const float* esW1 = (const float*)d_in[7];
  const float* esb1 = (const float*)d_in[8];
  const float* esW2 = (const float*)d_in[9];
  const float* esb2 = (const float*)d_in[10];
  const float* gW1 = (const float*)d_in[11];
  const float* gb1 = (const float*)d_in[12];
  const float* gW2 = (const float*)d_in[13];
  const float* gb2 = (const float*)d_in[14];
  const float* iW = (const float*)d_in[15];
  const float* ibv = (const float*)d_in[16];
  char* ws = (char*)d_ws;
  float* out = (float*)d_out;

  ct4_prep<<<1, 64, 0, stream>>>(etW1, etb1, etW2, etb2, esW1, esb1, esW2, esb2, ws);
  (void)hipFuncSetAttribute((const void*)ct4_main,
                            hipFuncAttributeMaxDynamicSharedMemorySize, SMEM_BYTES);
  ct4_main<<<GQ * 4, 512, SMEM_BYTES, stream>>>(ev, ts, mk, gW1, gb1, gW2, gb2, iW, ibv, out, ws);
}

// Round 13
// 3911.622 us; speedup vs baseline: 1.0379x; 1.0379x over previous
//
#include <hip/hip_runtime.h>
#include <stdint.h>

typedef unsigned short u16;
typedef unsigned char u8;
typedef unsigned long long u64;
typedef short s16x8 __attribute__((ext_vector_type(8)));
typedef float f32x4 __attribute__((ext_vector_type(4)));
typedef float f32x2 __attribute__((ext_vector_type(2)));
typedef unsigned int u32x4 __attribute__((ext_vector_type(4)));
typedef unsigned int u32x2 __attribute__((ext_vector_type(2)));

#define NB 128
#define NT 512
#define NH 256
#define GQ 8      // batch groups (16 rows each)
#define MBQ 16
#define STEPS 511

// ---- workspace layout (bytes) ----
#define WS_HBUF 0        // double-buffered h: 2 * GQ * MBQ * 256 * 2B = 131072
#define WS_X12  131072   // 12*64 floats = 3072
#define WS_BAR  134144   // 8 groups * 4 flags * 128B = 4096

// ---- dynamic LDS layout (bytes) ----
#define OFF_HA    0        // h tile A: 16 rows * 264 u16 = 8448
#define OFF_HB    8448     // h tile B: 8448  (-> 16896)
#define OFF_PRE   16896    // pre: 7 gates * 16 * 72 u16 = 16128 (-> 33024), shared A/B
#define OFF_G     33024    // gates: 7 * 16 * 68 f32 = 30464 (-> 63488), shared A/B
#define OFF_XC    63488    // xc table: 7 * 64 * 13 f32 = 23296 (-> 86784)
#define OFF_B2    86784    // g_b2 slice: 7*64 f32 = 1792 (-> 88576)
#define OFF_IW    88576    // i_W slice: 64 f32 = 256 (-> 88832)
#define OFF_X12   88832    // x12: 12*64 f32 = 3072 (-> 91904)
#define SMEM_BYTES 91904

__device__ __forceinline__ u16 f2bf(float f) {
  unsigned u = __float_as_uint(f);
  u += 0x7FFFu + ((u >> 16) & 1u);  // round-to-nearest-even
  return (u16)(u >> 16);
}
__device__ __forceinline__ float sigm(float x) { return 1.0f / (1.0f + __expf(-x)); }
__device__ __forceinline__ float tanh_fast(float x) {
  float e = __expf(2.0f * x);
  return 1.0f - 2.0f / (e + 1.0f);
}
__device__ __forceinline__ float softplus_f(float x) {
  return fmaxf(x, 0.0f) + __logf(1.0f + __expf(-fabsf(x)));
}
__device__ __forceinline__ int ald(const int* p) {
  return __hip_atomic_load(p, __ATOMIC_RELAXED, __HIP_MEMORY_SCOPE_AGENT);
}
__device__ __forceinline__ u64 ald64(const u64* p) {
  return __hip_atomic_load(p, __ATOMIC_RELAXED, __HIP_MEMORY_SCOPE_AGENT);
}

// ---------------- prep: 12 embeddings, zero h buf0, reset barrier flags ----------------
__global__ void ct4_prep(const float* __restrict__ etW1, const float* __restrict__ etb1,
                         const float* __restrict__ etW2, const float* __restrict__ etb2,
                         const float* __restrict__ esW1, const float* __restrict__ esb1,
                         const float* __restrict__ esW2, const float* __restrict__ esb2,
                         char* __restrict__ ws) {
  __shared__ float sT[4][64];
  __shared__ float sS[3][64];
  const int i = threadIdx.x;  // 64 threads
  #pragma unroll
  for (int e = 0; e < 4; ++e) sT[e][i] = tanhf(etW1[i * 4 + e] + etb1[i]);
  #pragma unroll
  for (int s = 0; s < 3; ++s) sS[s][i] = tanhf(esW1[i * 3 + s] + esb1[i]);
  __syncthreads();
  float te[4], se[3];
  #pragma unroll
  for (int e = 0; e < 4; ++e) {
    float a = etb2[i];
    for (int jj = 0; jj < 64; ++jj) a += sT[e][jj] * etW2[i * 64 + jj];
    te[e] = tanhf(a);
  }
  #pragma unroll
  for (int s = 0; s < 3; ++s) {
    float a = esb2[i];
    for (int jj = 0; jj < 64; ++jj) a += sS[s][jj] * esW2[i * 64 + jj];
    se[s] = tanhf(a);
  }
  float* x12 = (float*)(ws + WS_X12);
  #pragma unroll
  for (int e = 0; e < 4; ++e)
    #pragma unroll
    for (int s = 0; s < 3; ++s) x12[(e * 3 + s) * 64 + i] = te[e] + se[s];
  // zero h buffer parity 0 (all 8 groups)
  u32x4* hz = (u32x4*)(ws + WS_HBUF);
  u32x4 z = {0u, 0u, 0u, 0u};
  for (int p = i; p < 65536 / 16; p += 64) hz[p] = z;
  // reset barrier flags
  int* bars = (int*)(ws + WS_BAR);
  for (int p = i; p < 1024; p += 64) bars[p] = 0;
}

// ---------------- main persistent recurrence kernel ----------------
// 16 blocks x 512 threads. Block (p = bid&3, j = bid>>2) runs TWO batch groups
// (gA = p, gB = p+4) for hidden block j, phase-shifted so each group's exchange
// (agent-scope flag+pull, r8-verified protocol) hides under the other group's compute.
// Weights depend only on j -> both groups share the same register-resident fragments.
// Wave k (0..6) owns gate k; wave 7 is the exchange wave (pull B at iter start,
// pull A during top(B)). dt/idx come from tiny per-step L2-resident loads (no LDS tables).
__global__ __launch_bounds__(512, 1) void ct4_main(
    const int* __restrict__ ev, const float* __restrict__ ts, const int* __restrict__ mk,
    const float* __restrict__ gW1, const float* __restrict__ gb1,
    const float* __restrict__ gW2, const float* __restrict__ gb2,
    const float* __restrict__ iW, const float* __restrict__ ibp,
    float* __restrict__ out, char* __restrict__ ws) {
  extern __shared__ char smem[];
  u16* h_ldsA = (u16*)(smem + OFF_HA);        // [16][264]
  u16* h_ldsB = (u16*)(smem + OFF_HB);        // [16][264]
  float* g_lds = (float*)(smem + OFF_G);      // [7][16][68] (shared A/B, reused)
  float* xc_lds = (float*)(smem + OFF_XC);    // [(k*64+o)*13 + m]
  float* b2_lds = (float*)(smem + OFF_B2);    // [7][64]
  float* iw_lds = (float*)(smem + OFF_IW);    // [64]
  float* x12_lds = (float*)(smem + OFF_X12);  // [12][64]

  const int tid = threadIdx.x;
  const int bid = blockIdx.x;
  const int p = bid & 3;
  const int j = bid >> 2;
  const int gA = p, gB = p + 4;
  const int b0A = gA * MBQ, b0B = gB * MBQ;
  const int wave = tid >> 6;
  const int q = (tid >> 4) & 3;
  const int c = tid & 15;
  const int bb = tid >> 5;          // phase-C batch row
  const int o2 = (tid & 31) * 2;    // phase-C col pair

  u16* hbuf = (u16*)(ws + WS_HBUF);
  int* bars = (int*)(ws + WS_BAR);
  int* flagAp = bars + gA * 128 + j * 32;
  int* flagBp = bars + gB * 128 + j * 32;
  const int jr0 = 0 + (0 >= j), jr1 = 1 + (1 >= j), jr2 = 2 + (2 >= j);
  int* fA0 = bars + gA * 128 + jr0 * 32;
  int* fA1 = bars + gA * 128 + jr1 * 32;
  int* fA2 = bars + gA * 128 + jr2 * 32;
  int* fB0 = bars + gB * 128 + jr0 * 32;
  int* fB1 = bars + gB * 128 + jr1 * 32;
  int* fB2 = bars + gB * 128 + jr2 * 32;

  // ---- prologue ----
  for (int pz = tid; pz < 12 * 64; pz += 512) x12_lds[pz] = ((const float*)(ws + WS_X12))[pz];
  for (int pz = tid; pz < 2 * 16 * 264 / 2; pz += 512) ((unsigned*)(smem + OFF_HA))[pz] = 0u;
  if (tid < 448) {
    int kk = tid >> 6, o = tid & 63;
    b2_lds[kk * 64 + o] = gb2[kk * 256 + j * 64 + o];
  }
  if (tid < 64) iw_lds[tid] = iW[j * 256 + j * 64 + tid];
  const float ibj = ibp[j];
  __syncthreads();
  // xc table: xc[k][o][m] = g_b1[k][j*64+o] + sum_i x12[m][i] * W1[k][j*64+o][i]
  if (tid < 448) {
    int kk = tid >> 6, o = tid & 63;
    const float* row = gW1 + (size_t)(kk * 256 + j * 64 + o) * 320;
    float a[12];
    float bbias = gb1[kk * 256 + j * 64 + o];
    #pragma unroll
    for (int m = 0; m < 12; ++m) a[m] = bbias;
    for (int i = 0; i < 64; ++i) {
      float w = row[i];
      #pragma unroll
      for (int m = 0; m < 12; ++m) a[m] += x12_lds[m * 64 + i] * w;
    }
    #pragma unroll
    for (int m = 0; m < 12; ++m) xc_lds[(kk * 64 + o) * 13 + m] = a[m];
  }

  // weight fragments (bf16), natural K-slot order kt=0..7.
  s16x8 a1[4][8];  // W1 h-part: M=64 (o), K=256 (h)
  s16x8 a2[4][2];  // W2 block:  M=64 (o), K=64 (g)
  const int k = wave;
  if (wave < 7) {
    #pragma unroll
    for (int s = 0; s < 8; ++s)
      #pragma unroll
      for (int mt = 0; mt < 4; ++mt) {
        const float* pw = gW1 + (size_t)(k * 256 + j * 64 + 16 * mt + c) * 320 + 64 + 32 * s + 8 * q;
        union { s16x8 v; u16 u[8]; } fr;
        #pragma unroll
        for (int i = 0; i < 8; ++i) fr.u[i] = f2bf(pw[i]);
        a1[mt][s] = fr.v;
      }
    #pragma unroll
    for (int mt = 0; mt < 4; ++mt)
      #pragma unroll
      for (int kt = 0; kt < 2; ++kt) {
        const float* pw = gW2 + (size_t)(k * 256 + j * 64 + 16 * mt + c) * 256 + j * 64 + 32 * kt + 8 * q;
        union { s16x8 v; u16 u[8]; } fr;
        #pragma unroll
        for (int i = 0; i < 8; ++i) fr.u[i] = f2bf(pw[i]);
        a2[mt][kt] = fr.v;
      }
  }

  float ccA[2] = {0.f, 0.f}, cctA[2] = {0.f, 0.f};
  float ccB[2] = {0.f, 0.f}, cctB[2] = {0.f, 0.f};
  __syncthreads();

  const int O_CELL = NB * STEPS * 4;
  const int SZB = NB * STEPS * NH;
  const int O_CT = O_CELL + SZB;
  const int O_OUT = O_CT + SZB;
  const int O_DEC = O_OUT + SZB;

  // TOP: GEMM1 (8 K-slots) + tanh + GEMM2 for one group's h tile
  auto TOP = [&](const u16* hl, int midx) {
    f32x4 acc[4] = {};
    #pragma unroll
    for (int s = 0; s < 8; ++s) {
      s16x8 bf = *(const s16x8*)&hl[c * 264 + 32 * s + 8 * q];
      #pragma unroll
      for (int mt = 0; mt < 4; ++mt)
        acc[mt] = __builtin_amdgcn_mfma_f32_16x16x32_bf16(a1[mt][s], bf, acc[mt], 0, 0, 0);
    }
    u16* preW = (u16*)(smem + OFF_PRE) + k * (16 * 72);
    #pragma unroll
    for (int mt = 0; mt < 4; ++mt) {
      int o = 16 * mt + 4 * q;
      const float* xr = &xc_lds[(k * 64 + o) * 13 + midx];
      u16 u0 = f2bf(tanh_fast(acc[mt][0] + xr[0]));
      u16 u1 = f2bf(tanh_fast(acc[mt][1] + xr[13]));
      u16 u2 = f2bf(tanh_fast(acc[mt][2] + xr[26]));
      u16 u3 = f2bf(tanh_fast(acc[mt][3] + xr[39]));
      u32x2 pk;
      pk[0] = (unsigned)u0 | ((unsigned)u1 << 16);
      pk[1] = (unsigned)u2 | ((unsigned)u3 << 16);
      *(u32x2*)&preW[c * 72 + o] = pk;
    }
    f32x4 acc2[4] = {};
    #pragma unroll
    for (int kt = 0; kt < 2; ++kt) {
      s16x8 pf = *(const s16x8*)&preW[c * 72 + 32 * kt + 8 * q];
      #pragma unroll
      for (int mt = 0; mt < 4; ++mt)
        acc2[mt] = __builtin_amdgcn_mfma_f32_16x16x32_bf16(a2[mt][kt], pf, acc2[mt], 0, 0, 0);
    }
    #pragma unroll
    for (int mt = 0; mt < 4; ++mt)
      *(f32x4*)&g_lds[(k * 16 + c) * 68 + 16 * mt + 4 * q] = acc2[mt];
  };

  // PULL: poll 3 partner flags >= tgt, then copy 3x128B/row of remote h into hl
  auto PULL = [&](int tgt, int* q0, int* q1, int* q2, int parity, int gh, u16* hl) {
    const int l = tid & 63;
    const int row = l >> 2;
    const int segb = (l & 3) * 32;
    for (;;) {
      int f0 = ald(q0), f1 = ald(q1), f2 = ald(q2);
      if (f0 >= tgt && f1 >= tgt && f2 >= tgt) break;
      __builtin_amdgcn_s_sleep(1);
    }
    const char* rbase = (const char*)hbuf + ((size_t)(parity * GQ + gh) * MBQ + row) * 512 + segb;
    u64 dv[3][4];
    #pragma unroll
    for (int rb = 0; rb < 3; ++rb) {
      int jr = rb + (rb >= j);
      const u64* src = (const u64*)(rbase + jr * 128);
      #pragma unroll
      for (int kq = 0; kq < 4; ++kq) dv[rb][kq] = ald64(src + kq);
    }
    char* lbase = (char*)hl + row * 528 + segb;
    #pragma unroll
    for (int rb = 0; rb < 3; ++rb) {
      int jr = rb + (rb >= j);
      #pragma unroll
      for (int kq = 0; kq < 4; ++kq) *(u64*)(lbase + jr * 128 + 8 * kq) = dv[rb][kq];
    }
  };

  for (int t = 0; t < STEPS; ++t) {
    // per-step scalars (L2-resident; consumed >=250 cycles later)
    const int rA = (b0A + c) * NT + t, rB = (b0B + c) * NT + t;
    int evA = ev[rA], mkA = mk[rA];
    int evB = ev[rB], mkB = mk[rB];
    float dtA = ts[(b0A + bb) * NT + t + 1];
    float dtB = ts[(b0B + bb) * NT + t + 1];

    // ---- top(A) || pull B(t) ----
    if (wave < 7) TOP(h_ldsA, evA * 3 + mkA);
    else if (t > 0) PULL(t, fB0, fB1, fB2, t & 1, gB, h_ldsB);
    __syncthreads();  // g_lds(A) ready; h_ldsB(t) complete

    // ---- phase C (A) ----
    float ciA[2], ctnA[2], opvA[2], dcvA[2];
    float ipA = 0.f;
    {
      float G[7][2];
      #pragma unroll
      for (int kk = 0; kk < 7; ++kk) {
        f32x2 gg = *(const f32x2*)&g_lds[(kk * 16 + bb) * 68 + o2];
        G[kk][0] = gg[0] + b2_lds[kk * 64 + o2];
        G[kk][1] = gg[1] + b2_lds[kk * 64 + o2 + 1];
      }
      float hnv[2];
      #pragma unroll
      for (int e = 0; e < 2; ++e) {
        float inp = sigm(G[0][e]);
        float fg = sigm(G[1][e]);
        float op = sigm(G[2][e]);
        float itg = sigm(G[3][e]);
        float ftg = sigm(G[4][e]);
        float z = tanh_fast(G[5][e]);
        float dc = softplus_f(G[6][e]);
        float c_i = fg * ccA[e] + inp * z;
        float c_t = ftg * cctA[e] + itg * z;
        float edv = __expf(-dc * dtA);
        float c_n = c_t + (c_i - c_t) * edv;
        float h_n = op * tanh_fast(c_n);
        ccA[e] = c_n; cctA[e] = c_t;
        ciA[e] = c_i; ctnA[e] = c_t; opvA[e] = op; dcvA[e] = dc;
        hnv[e] = h_n;
        ipA += iw_lds[o2 + e] * h_n;
      }
      if (t < STEPS - 1) {
        unsigned hp = (unsigned)f2bf(hnv[0]) | ((unsigned)f2bf(hnv[1]) << 16);
        *(unsigned*)&h_ldsA[bb * 264 + j * 64 + o2] = hp;
        __hip_atomic_store(
            (unsigned*)&hbuf[((size_t)((((t + 1) & 1)) * GQ + gA) * MBQ + bb) * 256 + j * 64 + o2],
            hp, __ATOMIC_RELAXED, __HIP_MEMORY_SCOPE_AGENT);
      }
    }
    __syncthreads();  // drains A h-stores (vmcnt 0), orders h_ldsA local writes
    if (tid == 0 && t < STEPS - 1)
      __hip_atomic_store(flagAp, t + 1, __ATOMIC_RELAXED, __HIP_MEMORY_SCOPE_AGENT);
    {  // C2(A): output stores + intensity
      size_t base = ((size_t)(b0A + bb) * STEPS + t) * NH + j * 64 + o2;
      f32x2 v;
      v[0] = ciA[0];  v[1] = ciA[1];  *(f32x2*)&out[O_CELL + base] = v;
      v[0] = ctnA[0]; v[1] = ctnA[1]; *(f32x2*)&out[O_CT + base] = v;
      v[0] = opvA[0]; v[1] = opvA[1]; *(f32x2*)&out[O_OUT + base] = v;
      v[0] = dcvA[0]; v[1] = dcvA[1]; *(f32x2*)&out[O_DEC + base] = v;
      #pragma unroll
      for (int d = 1; d < 32; d <<= 1) ipA += __shfl_xor(ipA, d, 32);
      if ((tid & 31) == 0)
        out[((size_t)(b0A + bb) * STEPS + t) * 4 + j] = softplus_f(ipA + ibj);
    }

    // ---- top(B) || pull A(t+1) ----
    if (wave < 7) TOP(h_ldsB, evB * 3 + mkB);
    else if (t < STEPS - 1) PULL(t + 1, fA0, fA1, fA2, (t + 1) & 1, gA, h_ldsA);
    __syncthreads();  // g_lds(B) ready; h_ldsA(t+1) remote complete

    // ---- phase C (B) ----
    float ciB[2], ctnB[2], opvB[2], dcvB[2];
    float ipB = 0.f;
    {
      float G[7][2];
      #pragma unroll
      for (int kk = 0; kk < 7; ++kk) {
        f32x2 gg = *(const f32x2*)&g_lds[(kk * 16 + bb) * 68 + o2];
        G[kk][0] = gg[0] + b2_lds[kk * 64 + o2];
        G[kk][1] = gg[1] + b2_lds[kk * 64 + o2 + 1];
      }
      float hnv[2];
      #pragma unroll
      for (int e = 0; e < 2; ++e) {
        float inp = sigm(G[0][e]);
        float fg = sigm(G[1][e]);
        float op = sigm(G[2][e]);
        float itg = sigm(G[3][e]);
        float ftg = sigm(G[4][e]);
        float z = tanh_fast(G[5][e]);
        float dc = softplus_f(G[6][e]);
        float c_i = fg * ccB[e] + inp * z;
        float c_t = ftg * cctB[e] + itg * z;
        float edv = __expf(-dc * dtB);
        float c_n = c_t + (c_i - c_t) * edv;
        float h_n = op * tanh_fast(c_n);
        ccB[e] = c_n; cctB[e] = c_t;
        ciB[e] = c_i; ctnB[e] = c_t; opvB[e] = op; dcvB[e] = dc;
        hnv[e] = h_n;
        ipB += iw_lds[o2 + e] * h_n;
      }
      if (t < STEPS - 1) {
        unsigned hp = (unsigned)f2bf(hnv[0]) | ((unsigned)f2bf(hnv[1]) << 16);
        *(unsigned*)&h_ldsB[bb * 264 + j * 64 + o2] = hp;
        __hip_atomic_store(
            (unsigned*)&hbuf[((size_t)((((t + 1) & 1)) * GQ + gB) * MBQ + bb) * 256 + j * 64 + o2],
            hp, __ATOMIC_RELAXED, __HIP_MEMORY_SCOPE_AGENT);
      }
    }
    __syncthreads();  // drains B h-stores
    if (tid == 0 && t < STEPS - 1)
      __hip_atomic_store(flagBp, t + 1, __ATOMIC_RELAXED, __HIP_MEMORY_SCOPE_AGENT);
    {  // C2(B)
      size_t base = ((size_t)(b0B + bb) * STEPS + t) * NH + j * 64 + o2;
      f32x2 v;
      v[0] = ciB[0];  v[1] = ciB[1];  *(f32x2*)&out[O_CELL + base] = v;
      v[0] = ctnB[0]; v[1] = ctnB[1]; *(f32x2*)&out[O_CT + base] = v;
      v[0] = opvB[0]; v[1] = opvB[1]; *(f32x2*)&out[O_OUT + base] = v;
      v[0] = dcvB[0]; v[1] = dcvB[1]; *(f32x2*)&out[O_DEC + base] = v;
      #pragma unroll
      for (int d = 1; d < 32; d <<= 1) ipB += __shfl_xor(ipB, d, 32);
      if ((tid & 31) == 0)
        out[((size_t)(b0B + bb) * STEPS + t) * 4 + j] = softplus_f(ipB + ibj);
    }
  }
}

extern "C" void kernel_launch(void* const* d_in, const int* in_sizes, int n_in,
                              void* d_out, int out_size, void* d_ws, size_t ws_size,
                              hipStream_t stream) {
  const int* ev = (const int*)d_in[0];
  const float* ts = (const float*)d_in[1];
  const int* mk = (const int*)d_in[2];
  const float* etW1 = (const float*)d_in[3];
  const float* etb1 = (const float*)d_in[4];
  const float* etW2 = (const float*)d_in[5];
  const float* etb2 = (const float*)d_in[6];
  const float* esW1 = (const float*)d_in[7];
  const float* esb1 = (const float*)d_in[8];
  const float* esW2 = (const float*)d_in[9];
  const float* esb2 = (const float*)d_in[10];
  const float* gW1 = (const float*)d_in[11];
  const float* gb1 = (const float*)d_in[12];
  const float* gW2 = (const float*)d_in[13];
  const float* gb2 = (const float*)d_in[14];
  const float* iW = (const float*)d_in[15];
  const float* ibv = (const float*)d_in[16];
  char* ws = (char*)d_ws;
  float* out = (float*)d_out;

  ct4_prep<<<1, 64, 0, stream>>>(etW1, etb1, etW2, etb2, esW1, esb1, esW2, esb2, ws);
  (void)hipFuncSetAttribute((const void*)ct4_main,
                            hipFuncAttributeMaxDynamicSharedMemorySize, SMEM_BYTES);
  ct4_main<<<16, 512, SMEM_BYTES, stream>>>(ev, ts, mk, gW1, gb1, gW2, gb2, iW, ibv, out, ws);
}